// Round 2
// baseline (254.957 us; speedup 1.0000x reference)
//
#include <hip/hip_runtime.h>

// PoolingNms fused: 3 chained pool/unpool (k=3,5,6) on 16x1x1080x1920 fp32.
// Key fact: unpool puts each window max back at its own position, so after
// stage 1 the tensor is sparse (<=1 survivor per 3x3 cell, at its original
// location) and stages 2/3 are pure filters over the survivor set:
//   survive k=5 iff max among stage-1 survivors in your 5x5 cell,
//   survive k=6 iff max among 5x5 winners in your 6x6 cell.
// Since 3,5,6 all divide 30 (and 30 | 1080, 30 | 1920), no window ever
// crosses a 30-aligned boundary -> blocks of 30x240 are fully independent.
// Ties: jnp.argmax = first occurrence in row-major window order; packed
// pos (r<<8)|c compares lexicographically == row-major, so (val desc,
// pos asc) tie-break reproduces it bit-exactly.

#define IMG_H 1080
#define IMG_W 1920
#define TILE_H 30
#define TILE_W 240
#define NT 256

__global__ __launch_bounds__(NT) void pooling_nms_kernel(
    const float* __restrict__ x, float* __restrict__ out) {
    __shared__ float sval[800];   // stage-1 survivors: 10 x 80 grid of 3x3 cells
    __shared__ int   spos[800];   // packed (r<<8)|c, block-local r 0..29, c 0..239
    __shared__ float w5val[288];  // stage-2 winners: 6 x 48 grid of 5x5 cells
    __shared__ int   w5pos[288];

    const int t = threadIdx.x;
    const size_t base = (size_t)blockIdx.z * ((size_t)IMG_H * IMG_W) +
                        (size_t)blockIdx.y * TILE_H * IMG_W +
                        (size_t)blockIdx.x * TILE_W;
    const float* src = x + base;
    float* dst = out + base;

    // ---- Phase 1a: stage-1 (k=3) survivors, read straight from global.
    // Wave-adjacent threads handle adjacent windows -> each row read is a
    // contiguous 768B segment per wave (coalesced 12B/lane).
    for (int w = t; w < 800; w += NT) {
        const int wr = w / 80;       // 0..9
        const int wc = w - wr * 80;  // 0..79
        const int r0 = wr * 3, c0 = wc * 3;
        float mx = -1.0f;
        int am = 0;
#pragma unroll
        for (int r = 0; r < 3; ++r) {
            const float* p = src + (size_t)(r0 + r) * IMG_W + c0;
            const float v0 = p[0], v1 = p[1], v2 = p[2];
            if (v0 > mx) { mx = v0; am = ((r0 + r) << 8) | c0; }
            if (v1 > mx) { mx = v1; am = ((r0 + r) << 8) | (c0 + 1); }
            if (v2 > mx) { mx = v2; am = ((r0 + r) << 8) | (c0 + 2); }
        }
        sval[w] = mx;
        spos[w] = am;
    }

    // ---- Phase 1b: zero-fill the block's output region (coalesced float4).
    for (int i = t; i < (TILE_H * TILE_W / 4); i += NT) {
        const int r = i / (TILE_W / 4);
        const int c4 = i - r * (TILE_W / 4);
        *reinterpret_cast<float4*>(dst + (size_t)r * IMG_W + c4 * 4) =
            make_float4(0.f, 0.f, 0.f, 0.f);
    }
    __syncthreads();  // drains vmcnt -> zero-fill globally ordered before phase 3 scatter

    // ---- Phase 2: stage-2 (k=5). Winner among stage-1 survivors per 5x5 cell.
    for (int w = t; w < 288; w += NT) {
        const int a = w / 48;       // 5-cell row 0..5
        const int b = w - a * 48;   // 5-cell col 0..47
        const int rlo = (5 * a) / 3, rhi = (5 * a + 4) / 3;
        const int clo = (5 * b) / 3, chi = (5 * b + 4) / 3;
        float bv = -1.0f;
        int bp = 0x7FFFFFFF;
        for (int r3 = rlo; r3 <= rhi; ++r3)
            for (int c3 = clo; c3 <= chi; ++c3) {
                const int idx = r3 * 80 + c3;
                const float v = sval[idx];
                const int p = spos[idx];
                const int r = p >> 8, c = p & 255;
                const bool in =
                    ((unsigned)(r - 5 * a) < 5u) & ((unsigned)(c - 5 * b) < 5u);
                if (in && (v > bv || (v == bv && p < bp))) { bv = v; bp = p; }
            }
        w5val[w] = bv;   // -1 if the 5x5 cell holds no survivor
        w5pos[w] = bp;
    }
    __syncthreads();

    // ---- Phase 3: stage-3 (k=6). Exactly 4 candidate 5-cells per 6x6 cell;
    // final winners scatter to global (hits just-zeroed L2 lines).
    for (int w = t; w < 200; w += NT) {
        const int a = w / 40;       // 6-cell row 0..4
        const int b = w - a * 40;   // 6-cell col 0..39
        const int rlo = (6 * a) / 5;
        const int clo = (6 * b) / 5;
        float bv = -1.0f;
        int bp = 0x7FFFFFFF;
#pragma unroll
        for (int dr = 0; dr < 2; ++dr)
#pragma unroll
            for (int dc = 0; dc < 2; ++dc) {
                const int idx = (rlo + dr) * 48 + (clo + dc);
                const float v = w5val[idx];
                const int p = w5pos[idx];
                const int r = p >> 8, c = p & 255;
                const bool in = (v >= 0.0f) &
                                ((unsigned)(r - 6 * a) < 6u) &
                                ((unsigned)(c - 6 * b) < 6u);
                if (in && (v > bv || (v == bv && p < bp))) { bv = v; bp = p; }
            }
        if (bv >= 0.0f) {
            const int r = bp >> 8, c = bp & 255;
            dst[(size_t)r * IMG_W + c] = bv;
        }
    }
}

extern "C" void kernel_launch(void* const* d_in, const int* in_sizes, int n_in,
                              void* d_out, int out_size, void* d_ws, size_t ws_size,
                              hipStream_t stream) {
    const float* x = (const float*)d_in[0];
    float* out = (float*)d_out;
    dim3 grid(IMG_W / TILE_W, IMG_H / TILE_H, 16);  // 8 x 36 x 16 = 4608
    pooling_nms_kernel<<<grid, NT, 0, stream>>>(x, out);
}

// Round 3
// 239.869 us; speedup vs baseline: 1.0629x; 1.0629x over previous
//
#include <hip/hip_runtime.h>

// PoolingNms fused: 3 chained pool/unpool (k=3,5,6) on 16x1x1080x1920 fp32.
// Unpool puts each window max back at its own position -> after stage 1 the
// tensor is sparse (<=1 survivor per 3x3 cell, at its original location) and
// stages 2/3 are pure filters over the survivor set. 3,5,6 all divide 30 and
// 30 | 1080, 30 | 1920 -> 30x240 blocks are fully independent.
// Tie-break: packed pos (r<<8)|c ascending == row-major first-occurrence ==
// jnp.argmax semantics, bit-exact.
//
// R3 change vs R2: output composed in a 28.8KB LDS tile and written ONCE as a
// sequential float4 stream (R2's global zero-fill + scattered dword stores
// risked L2 evictions between fill and scatter -> 64B line refetches).

#define IMG_H 1080
#define IMG_W 1920
#define TILE_H 30
#define TILE_W 240
#define NT 256

__global__ __launch_bounds__(NT) void pooling_nms_kernel(
    const float* __restrict__ x, float* __restrict__ out) {
    __shared__ float tile[TILE_H * TILE_W];  // compose buffer, 28.8 KB
    __shared__ float sval[800];   // stage-1 survivors (10 x 80 grid of 3x3)
    __shared__ int   spos[800];   // packed (r<<8)|c, block-local
    __shared__ float w5val[288];  // stage-2 winners (6 x 48 grid of 5x5)
    __shared__ int   w5pos[288];

    const int t = threadIdx.x;
    const size_t base = (size_t)blockIdx.z * ((size_t)IMG_H * IMG_W) +
                        (size_t)blockIdx.y * TILE_H * IMG_W +
                        (size_t)blockIdx.x * TILE_W;
    const float* src = x + base;
    float* dst = out + base;

    // ---- Phase 0a: zero the LDS compose tile (float4, conflict-free).
    float4* tile4 = reinterpret_cast<float4*>(tile);
    for (int i = t; i < (TILE_H * TILE_W / 4); i += NT)
        tile4[i] = make_float4(0.f, 0.f, 0.f, 0.f);

    // ---- Phase 0b: stage-1 (k=3) survivors, streamed from global.
    // Lane-adjacent windows -> 12 contiguous bytes/lane, fully coalesced.
    for (int w = t; w < 800; w += NT) {
        const int wr = w / 80;       // 0..9
        const int wc = w - wr * 80;  // 0..79
        const int r0 = wr * 3, c0 = wc * 3;
        float mx = -1.0f;  // inputs are >= 0
        int am = 0;
#pragma unroll
        for (int r = 0; r < 3; ++r) {
            const float* p = src + (size_t)(r0 + r) * IMG_W + c0;
            const float v0 = p[0], v1 = p[1], v2 = p[2];
            if (v0 > mx) { mx = v0; am = ((r0 + r) << 8) | c0; }
            if (v1 > mx) { mx = v1; am = ((r0 + r) << 8) | (c0 + 1); }
            if (v2 > mx) { mx = v2; am = ((r0 + r) << 8) | (c0 + 2); }
        }
        sval[w] = mx;
        spos[w] = am;
    }
    __syncthreads();

    // ---- Phase 2: stage-2 (k=5). Winner among stage-1 survivors per 5x5 cell.
    for (int w = t; w < 288; w += NT) {
        const int a = w / 48;       // 5-cell row 0..5
        const int b = w - a * 48;   // 5-cell col 0..47
        const int rlo = (5 * a) / 3, rhi = (5 * a + 4) / 3;
        const int clo = (5 * b) / 3, chi = (5 * b + 4) / 3;
        float bv = -1.0f;
        int bp = 0x7FFFFFFF;
        for (int r3 = rlo; r3 <= rhi; ++r3)
            for (int c3 = clo; c3 <= chi; ++c3) {
                const int idx = r3 * 80 + c3;
                const float v = sval[idx];
                const int p = spos[idx];
                const int r = p >> 8, c = p & 255;
                const bool in =
                    ((unsigned)(r - 5 * a) < 5u) & ((unsigned)(c - 5 * b) < 5u);
                if (in && (v > bv || (v == bv && p < bp))) { bv = v; bp = p; }
            }
        w5val[w] = bv;   // -1 if the 5x5 cell holds no survivor
        w5pos[w] = bp;
    }
    __syncthreads();

    // ---- Phase 3: stage-3 (k=6). Exactly 4 candidate 5-cells per 6x6 cell;
    // winners scatter into the LDS compose tile.
    for (int w = t; w < 200; w += NT) {
        const int a = w / 40;       // 6-cell row 0..4
        const int b = w - a * 40;   // 6-cell col 0..39
        const int rlo = (6 * a) / 5;
        const int clo = (6 * b) / 5;
        float bv = -1.0f;
        int bp = 0x7FFFFFFF;
#pragma unroll
        for (int dr = 0; dr < 2; ++dr)
#pragma unroll
            for (int dc = 0; dc < 2; ++dc) {
                const int idx = (rlo + dr) * 48 + (clo + dc);
                const float v = w5val[idx];
                const int p = w5pos[idx];
                const int r = p >> 8, c = p & 255;
                const bool in = (v >= 0.0f) &
                                ((unsigned)(r - 6 * a) < 6u) &
                                ((unsigned)(c - 6 * b) < 6u);
                if (in && (v > bv || (v == bv && p < bp))) { bv = v; bp = p; }
            }
        if (bv >= 0.0f) {
            const int r = bp >> 8, c = bp & 255;
            tile[r * TILE_W + c] = bv;
        }
    }
    __syncthreads();

    // ---- Phase 4: single sequential float4 output stream.
    for (int i = t; i < (TILE_H * TILE_W / 4); i += NT) {
        const int r = i / (TILE_W / 4);
        const int c4 = i - r * (TILE_W / 4);
        *reinterpret_cast<float4*>(dst + (size_t)r * IMG_W + c4 * 4) = tile4[i];
    }
}

extern "C" void kernel_launch(void* const* d_in, const int* in_sizes, int n_in,
                              void* d_out, int out_size, void* d_ws, size_t ws_size,
                              hipStream_t stream) {
    const float* x = (const float*)d_in[0];
    float* out = (float*)d_out;
    dim3 grid(IMG_W / TILE_W, IMG_H / TILE_H, 16);  // 8 x 36 x 16 = 4608
    pooling_nms_kernel<<<grid, NT, 0, stream>>>(x, out);
}